// Round 1
// baseline (1142.057 us; speedup 1.0000x reference)
//
#include <hip/hip_runtime.h>
#include <math.h>

// Linear attention forward, fp32 baseline (correctness-first).
// B=8, L=S=8192, D=256, H=8, hd=32.

#define B_ 8
#define S_ 8192
#define D_ 256
#define H_ 8
#define EPS_ 1e-6f
#define TT 64            // tokens per block tile
#define KC 16            // k-chunk for GEMM staging
#define NCHUNK (D_ / KC) // 16

// LDS layout (floats):
//  x_c : [TT][KC]         1024
//  w_t : [256][WT_STR]   4608   (WT_STR=18: b64 reads 2-way-free banks)
//  a_t : [TT][D_]        16384  (kf in kA, qf in kB)
//  b_t : [TT][D_]        16384  (v in kA, vo in kB)
#define XC_OFF 0
#define WT_STR 18
#define WT_OFF 1024
#define AT_OFF (1024 + 256 * WT_STR)   // 5632
#define BT_OFF (AT_OFF + TT * D_)      // 22016
#define LDS_FLOATS (BT_OFF + TT * D_)  // 38400
#define LDS_BYTES (LDS_FLOATS * 4)     // 153600 (< 160 KiB)

__device__ __forceinline__ void stage_w(float* lds, const float* __restrict__ Wg, int kc) {
  const int r0 = threadIdx.x >> 2, seg = threadIdx.x & 3;
#pragma unroll
  for (int rep = 0; rep < 4; ++rep) {
    const int row = rep * 64 + r0;
    float4 v = *(const float4*)(Wg + (size_t)row * D_ + kc * KC + seg * 4);
    float* dst = lds + WT_OFF + row * WT_STR + seg * 4;
    // float2 stores: row*18+seg*4 is only 8B-aligned for odd rows
    *(float2*)dst = make_float2(v.x, v.y);
    *(float2*)(dst + 2) = make_float2(v.z, v.w);
  }
}

// C[64 tok][256 out] = X[64][256] @ W[256 out][256 k]^T, 8x8 per thread.
// Thread (og=tid&31, tg=tid>>5): tokens tg*8..+7, outs og+32*j (j=0..7).
template <bool X_FROM_LDS>
__device__ __forceinline__ void gemm_acc(float* lds, int tg, int og,
                                         const float* __restrict__ Xg,
                                         const float* __restrict__ Wg,
                                         float acc[8][8]) {
#pragma unroll
  for (int i = 0; i < 8; ++i)
#pragma unroll
    for (int j = 0; j < 8; ++j) acc[i][j] = 0.f;

#pragma unroll 1
  for (int kc = 0; kc < NCHUNK; ++kc) {
    if constexpr (!X_FROM_LDS) {
      const int t = threadIdx.x >> 2, seg = threadIdx.x & 3;
      float4 v = *(const float4*)(Xg + (size_t)t * D_ + kc * KC + seg * 4);
      *(float4*)(lds + XC_OFF + t * KC + seg * 4) = v;
    }
    stage_w(lds, Wg, kc);
    __syncthreads();
#pragma unroll
    for (int kk = 0; kk < KC; kk += 4) {
      float4 xv[8];
#pragma unroll
      for (int i = 0; i < 8; ++i) {
        if constexpr (X_FROM_LDS)
          xv[i] = *(const float4*)(lds + BT_OFF + (tg * 8 + i) * D_ + kc * KC + kk);
        else
          xv[i] = *(const float4*)(lds + XC_OFF + (tg * 8 + i) * KC + kk);
      }
      float2 wa[8], wb[8];
#pragma unroll
      for (int j = 0; j < 8; ++j) {
        const float* wr = lds + WT_OFF + (og + 32 * j) * WT_STR + kk;
        wa[j] = *(const float2*)wr;
        wb[j] = *(const float2*)(wr + 2);
      }
#pragma unroll
      for (int i = 0; i < 8; ++i)
#pragma unroll
        for (int j = 0; j < 8; ++j) {
          acc[i][j] = fmaf(xv[i].x, wa[j].x, acc[i][j]);
          acc[i][j] = fmaf(xv[i].y, wa[j].y, acc[i][j]);
          acc[i][j] = fmaf(xv[i].z, wb[j].x, acc[i][j]);
          acc[i][j] = fmaf(xv[i].w, wb[j].y, acc[i][j]);
        }
    }
    __syncthreads();
  }
}

// kA: K/V projections + feature map + KV,Ksum accumulation.
__global__ void __launch_bounds__(256, 1)
kA(const float* __restrict__ keys, const float* __restrict__ values,
   const float* __restrict__ kmask,
   const float* __restrict__ Wk, const float* __restrict__ bk,
   const float* __restrict__ Wv, const float* __restrict__ bv,
   float* __restrict__ KV, float* __restrict__ Ksum) {
  extern __shared__ float lds[];
  const int b = blockIdx.y, t0 = blockIdx.x * TT;
  const int tid = threadIdx.x, og = tid & 31, tg = tid >> 5;
  float acc[8][8];
  float msk[8];
#pragma unroll
  for (int i = 0; i < 8; ++i) msk[i] = kmask[(size_t)b * S_ + t0 + tg * 8 + i];

  // K projection -> elu+1 -> mask -> a_t
  gemm_acc<false>(lds, tg, og, keys + ((size_t)b * S_ + t0) * D_, Wk, acc);
#pragma unroll
  for (int j = 0; j < 8; ++j) {
    const float bias = bk[og + 32 * j];
#pragma unroll
    for (int i = 0; i < 8; ++i) {
      float f = acc[i][j] + bias;
      f = (f > 0.f) ? (f + 1.f) : expf(f);
      lds[AT_OFF + (tg * 8 + i) * D_ + og + 32 * j] = f * msk[i];
    }
  }
  // V projection -> mask -> b_t
  gemm_acc<false>(lds, tg, og, values + ((size_t)b * S_ + t0) * D_, Wv, acc);
#pragma unroll
  for (int j = 0; j < 8; ++j) {
    const float bias = bv[og + 32 * j];
#pragma unroll
    for (int i = 0; i < 8; ++i)
      lds[BT_OFF + (tg * 8 + i) * D_ + og + 32 * j] = (acc[i][j] + bias) * msk[i];
  }
  __syncthreads();

  // Ksum: column tid over 64 tokens
  {
    float s = 0.f;
#pragma unroll 8
    for (int t = 0; t < TT; ++t) s += lds[AT_OFF + t * D_ + tid];
    atomicAdd(&Ksum[b * D_ + tid], s);
  }
  // KV[b][m][h][d]: thread (h=tid>>5, dg=(tid>>3)&3, mg=tid&7) owns 4m x 8d
  {
    const int h = tid >> 5, dg = (tid >> 3) & 3, mg = tid & 7;
    float kva[4][8];
#pragma unroll
    for (int im = 0; im < 4; ++im)
#pragma unroll
      for (int jd = 0; jd < 8; ++jd) kva[im][jd] = 0.f;
#pragma unroll 4
    for (int t = 0; t < TT; ++t) {
      float4 vv = *(const float4*)&lds[BT_OFF + t * D_ + h * 32 + mg * 4];
      float4 ka = *(const float4*)&lds[AT_OFF + t * D_ + h * 32 + dg * 8];
      float4 kb = *(const float4*)&lds[AT_OFF + t * D_ + h * 32 + dg * 8 + 4];
      const float vvp[4] = {vv.x, vv.y, vv.z, vv.w};
      const float kp[8] = {ka.x, ka.y, ka.z, ka.w, kb.x, kb.y, kb.z, kb.w};
#pragma unroll
      for (int im = 0; im < 4; ++im)
#pragma unroll
        for (int jd = 0; jd < 8; ++jd)
          kva[im][jd] = fmaf(vvp[im], kp[jd], kva[im][jd]);
    }
#pragma unroll
    for (int im = 0; im < 4; ++im)
#pragma unroll
      for (int jd = 0; jd < 8; ++jd)
        atomicAdd(&KV[(((size_t)b * 32 + mg * 4 + im) * H_ + h) * 32 + dg * 8 + jd],
                  kva[im][jd]);
  }
}

// kB: Q projection + feature map + numerator/Z + output GEMM.
__global__ void __launch_bounds__(256, 1)
kB(const float* __restrict__ queries, const float* __restrict__ qmask,
   const float* __restrict__ Wq, const float* __restrict__ bq,
   const float* __restrict__ Wm, const float* __restrict__ bm,
   const float* __restrict__ KV, const float* __restrict__ Ksum,
   float* __restrict__ out) {
  extern __shared__ float lds[];
  const int b = blockIdx.y, t0 = blockIdx.x * TT;
  const int tid = threadIdx.x, og = tid & 31, tg = tid >> 5;
  float acc[8][8];

  gemm_acc<false>(lds, tg, og, queries + ((size_t)b * S_ + t0) * D_, Wq, acc);
#pragma unroll
  for (int j = 0; j < 8; ++j) {
    const float bias = bq[og + 32 * j];
#pragma unroll
    for (int i = 0; i < 8; ++i) {
      float f = acc[i][j] + bias;
      f = (f > 0.f) ? (f + 1.f) : expf(f);
      const float qm = qmask[(size_t)b * S_ + t0 + tg * 8 + i];
      lds[AT_OFF + (tg * 8 + i) * D_ + og + 32 * j] = f * qm;
    }
  }
  __syncthreads();

  // numerator + Z; m = og (qf reads wave-uniform -> broadcast, conflict-free)
  {
    const int m = og;
#pragma unroll 1
    for (int h = 0; h < H_; ++h) {
      float4 ks4[8], kv4[8];
#pragma unroll
      for (int d4 = 0; d4 < 8; ++d4) {
        ks4[d4] = *(const float4*)&Ksum[(b * H_ + h) * 32 + d4 * 4];
        kv4[d4] = *(const float4*)&KV[(((size_t)b * 32 + m) * H_ + h) * 32 + d4 * 4];
      }
      float num[8], zz[8];
#pragma unroll
      for (int i = 0; i < 8; ++i) { num[i] = 0.f; zz[i] = 0.f; }
#pragma unroll
      for (int d4 = 0; d4 < 8; ++d4) {
#pragma unroll
        for (int i = 0; i < 8; ++i) {
          float4 qv = *(const float4*)&lds[AT_OFF + (tg * 8 + i) * D_ + h * 32 + d4 * 4];
          num[i] = fmaf(qv.x, kv4[d4].x, num[i]);
          num[i] = fmaf(qv.y, kv4[d4].y, num[i]);
          num[i] = fmaf(qv.z, kv4[d4].z, num[i]);
          num[i] = fmaf(qv.w, kv4[d4].w, num[i]);
          zz[i] = fmaf(qv.x, ks4[d4].x, zz[i]);
          zz[i] = fmaf(qv.y, ks4[d4].y, zz[i]);
          zz[i] = fmaf(qv.z, ks4[d4].z, zz[i]);
          zz[i] = fmaf(qv.w, ks4[d4].w, zz[i]);
        }
      }
#pragma unroll
      for (int i = 0; i < 8; ++i)
        lds[BT_OFF + (tg * 8 + i) * D_ + h * 32 + m] = num[i] / (zz[i] + EPS_);
    }
  }
  __syncthreads();

  // out = vo @ Wm^T + bm
  gemm_acc<true>(lds, tg, og, nullptr, Wm, acc);
#pragma unroll
  for (int j = 0; j < 8; ++j) {
    const float bias = bm[og + 32 * j];
#pragma unroll
    for (int i = 0; i < 8; ++i)
      out[((size_t)b * S_ + t0 + tg * 8 + i) * D_ + og + 32 * j] = acc[i][j] + bias;
  }
}

extern "C" void kernel_launch(void* const* d_in, const int* in_sizes, int n_in,
                              void* d_out, int out_size, void* d_ws, size_t ws_size,
                              hipStream_t stream) {
  const float* queries = (const float*)d_in[0];
  const float* keys    = (const float*)d_in[1];
  const float* values  = (const float*)d_in[2];
  const float* qmask   = (const float*)d_in[3];
  const float* kmask   = (const float*)d_in[4];
  const float* Wq = (const float*)d_in[5];
  const float* bq = (const float*)d_in[6];
  const float* Wk = (const float*)d_in[7];
  const float* bk = (const float*)d_in[8];
  const float* Wv = (const float*)d_in[9];
  const float* bv = (const float*)d_in[10];
  const float* Wm = (const float*)d_in[11];
  const float* bm = (const float*)d_in[12];
  float* out = (float*)d_out;

  const size_t kv_floats = (size_t)B_ * 32 * H_ * 32;  // 65536
  const size_t ks_floats = (size_t)B_ * D_;            // 2048
  if (ws_size < (kv_floats + ks_floats) * sizeof(float)) return;
  float* KV = (float*)d_ws;
  float* Ksum = KV + kv_floats;

  hipMemsetAsync(d_ws, 0, (kv_floats + ks_floats) * sizeof(float), stream);
  hipFuncSetAttribute(reinterpret_cast<const void*>(kA),
                      hipFuncAttributeMaxDynamicSharedMemorySize, LDS_BYTES);
  hipFuncSetAttribute(reinterpret_cast<const void*>(kB),
                      hipFuncAttributeMaxDynamicSharedMemorySize, LDS_BYTES);

  dim3 grid(S_ / TT, B_), block(256);
  kA<<<grid, block, LDS_BYTES, stream>>>(keys, values, kmask, Wk, bk, Wv, bv, KV, Ksum);
  kB<<<grid, block, LDS_BYTES, stream>>>(queries, qmask, Wq, bq, Wm, bm, KV, Ksum, out);
}

// Round 2
// 306.573 us; speedup vs baseline: 3.7252x; 3.7252x over previous
//
#include <hip/hip_runtime.h>
#include <math.h>

// Linear attention forward, bf16-MFMA version.
// B=8, L=S=8192, D=256, H=8, hd=32.
//
// kPrep: W[4] fp32 -> bf16 fragment-major layout Wf[w][g][o][8] in ws
// kA:    K/V projections (MFMA) + elu+1 + mask + per-head KV/Ksum (MFMA,
//        register-accumulated over 2 tiles, partial-stored to ws)
// kR:    reduce 64 block-partials per batch -> KV[b][h][m][d], Ksum[b][d]
// kB:    Q projection (flipped MFMA) + feature map + num/Z MFMA vs hoisted
//        KV/Ksum frags + divide + output GEMM (MFMA) + coalesced f32 stores.

#define B_ 8
#define S_ 8192
#define D_ 256
#define H_ 8
#define EPS_ 1e-6f

typedef short short8 __attribute__((ext_vector_type(8)));
typedef float f32x16 __attribute__((ext_vector_type(16)));
typedef float f32x4 __attribute__((ext_vector_type(4)));

// LDS map (per block): [0,32KB) bufA (Xf staging / vF / voF)
//                      [32KB,64KB) bufB (kfF / qfF)
//                      [64KB, +256B) mask tile, kB: +1KB bias
#define LDSA_OFF 0
#define LDSB_OFF 32768
#define LDSM_OFF 65536
#define LDSBQ_OFF 65792
#define LDS_KA 65792
#define LDS_KB 66816

__device__ __forceinline__ unsigned short f2bf(float f) {
  union { float f; unsigned u; } v; v.f = f;
  return (unsigned short)((v.u + 0x7fffu + ((v.u >> 16) & 1u)) >> 16);
}

// Stage a 64x256 fp32 tile -> bf16 chunk layout in LDS:
// chunk c = g*64 + (tok ^ (g&31)), 16B = X[tok][g*8 .. g*8+7].
// Global loads are flat float4 (perfectly coalesced); LDS writes conflict-free.
__device__ __forceinline__ void stage_tile(const float* __restrict__ src,
                                           char* __restrict__ ldsA, int tid) {
  const float4* s4 = (const float4*)src;
#pragma unroll
  for (int i = 0; i < 16; ++i) {
    float4 v = s4[i * 256 + tid];
    int f = i * 256 + tid;
    int tok = f >> 6, r = f & 63, g = r >> 1, j = r & 1;
    ushort4 h4 = make_ushort4(f2bf(v.x), f2bf(v.y), f2bf(v.z), f2bf(v.w));
    *(ushort4*)(ldsA + ((g * 64 + (tok ^ (g & 31))) * 16 + j * 8)) = h4;
  }
}

__global__ void kPrep(const float* __restrict__ Wq, const float* __restrict__ Wk,
                      const float* __restrict__ Wv, const float* __restrict__ Wm,
                      unsigned short* __restrict__ Wf) {
  int idx = blockIdx.x * 256 + threadIdx.x;  // 32768 = 4*32*256
  int wsel = idx >> 13, g = (idx >> 8) & 31, o = idx & 255;
  const float* W = wsel == 0 ? Wq : wsel == 1 ? Wk : wsel == 2 ? Wv : Wm;
  const float* p = W + o * 256 + g * 8;
  ushort4 a = make_ushort4(f2bf(p[0]), f2bf(p[1]), f2bf(p[2]), f2bf(p[3]));
  ushort4 c = make_ushort4(f2bf(p[4]), f2bf(p[5]), f2bf(p[6]), f2bf(p[7]));
  *(ushort4*)(Wf + (size_t)idx * 8) = a;
  *(ushort4*)(Wf + (size_t)idx * 8 + 4) = c;
}

// kA: grid (64, B_), 256 threads. Block handles tiles {2*blk, 2*blk+1}.
__global__ void __launch_bounds__(256, 2)
kA(const float* __restrict__ keys, const float* __restrict__ values,
   const float* __restrict__ kmask,
   const float* __restrict__ bk, const float* __restrict__ bv,
   const short8* __restrict__ WfK, const short8* __restrict__ WfV,
   float* __restrict__ kvpart, float* __restrict__ kspart,
   float* __restrict__ KV, float* __restrict__ Ksum, int use_atomic) {
  extern __shared__ char lds[];
  char* ldsA = lds + LDSA_OFF;
  char* ldsB = lds + LDSB_OFF;
  float* ldsM = (float*)(lds + LDSM_OFF);
  const int tid = threadIdx.x;
  const int w = tid >> 6, lane = tid & 63, lo = lane & 31, kg = lane >> 5;
  const int blk = blockIdx.x, b = blockIdx.y;

  const float bk0 = bk[w * 64 + lo], bk1 = bk[w * 64 + 32 + lo];
  const float bv0 = bv[w * 64 + lo], bv1 = bv[w * 64 + 32 + lo];

  f32x16 kvacc[2];
#pragma unroll
  for (int hh = 0; hh < 2; ++hh)
#pragma unroll
    for (int i = 0; i < 16; ++i) kvacc[hh][i] = 0.f;
  float ksacc0 = 0.f, ksacc1 = 0.f;

  for (int it = 0; it < 2; ++it) {
    const int t0 = (blk * 2 + it) * 64;
    __syncthreads();  // prev-tile LDS readers done before restaging
    stage_tile(keys + ((size_t)b * S_ + t0) * D_, ldsA, tid);
    if (tid < 64) ldsM[tid] = kmask[(size_t)b * S_ + t0 + tid];
    __syncthreads();

    // ---- K projection (standard): D[tok][o] = X * Wk^T ----
    f32x16 acc[2][2];
#pragma unroll
    for (int mt = 0; mt < 2; ++mt)
#pragma unroll
      for (int nt = 0; nt < 2; ++nt)
#pragma unroll
        for (int i = 0; i < 16; ++i) acc[mt][nt][i] = 0.f;

#pragma unroll 2
    for (int ks = 0; ks < 16; ++ks) {
      const int g = 2 * ks + kg;
      short8 af[2], bf[2];
#pragma unroll
      for (int mt = 0; mt < 2; ++mt) {
        int tokb = mt * 32 + lo;
        af[mt] = *(const short8*)(ldsA + (g * 64 + (tokb ^ (g & 31))) * 16);
      }
#pragma unroll
      for (int nt = 0; nt < 2; ++nt) bf[nt] = WfK[g * 256 + w * 64 + nt * 32 + lo];
#pragma unroll
      for (int mt = 0; mt < 2; ++mt)
#pragma unroll
        for (int nt = 0; nt < 2; ++nt)
          acc[mt][nt] = __builtin_amdgcn_mfma_f32_32x32x16_bf16(af[mt], bf[nt],
                                                                acc[mt][nt], 0, 0, 0);
    }
    __syncthreads();  // ldsA (K) reads done -> V may restage

    // stage V early (HBM latency hides under epilogue VALU)
    stage_tile(values + ((size_t)b * S_ + t0) * D_, ldsA, tid);

    // K epilogue: bias + elu+1 + mask -> kfF (ldsB, wave-private d-range)
#pragma unroll
    for (int mt = 0; mt < 2; ++mt)
#pragma unroll
      for (int nt = 0; nt < 2; ++nt) {
        const float bias = nt ? bk1 : bk0;
        const int o = w * 64 + nt * 32 + lo;
#pragma unroll
        for (int q = 0; q < 4; ++q) {
          float vv[4];
#pragma unroll
          for (int j2 = 0; j2 < 4; ++j2) {
            int r = 4 * q + j2;
            int tok = 8 * q + 4 * kg + 32 * mt + j2;
            float f = acc[mt][nt][r] + bias;
            f = f > 0.f ? f + 1.f : __expf(f);
            f *= ldsM[tok];
            if (nt == 0) ksacc0 += f; else ksacc1 += f;
            vv[j2] = f;
          }
          *(ushort4*)(ldsB + ((q + 4 * mt) * 256 + o) * 16 + kg * 8) =
              make_ushort4(f2bf(vv[0]), f2bf(vv[1]), f2bf(vv[2]), f2bf(vv[3]));
        }
      }
    __syncthreads();  // V staged

    // ---- V projection ----
#pragma unroll
    for (int mt = 0; mt < 2; ++mt)
#pragma unroll
      for (int nt = 0; nt < 2; ++nt)
#pragma unroll
        for (int i = 0; i < 16; ++i) acc[mt][nt][i] = 0.f;
#pragma unroll 2
    for (int ks = 0; ks < 16; ++ks) {
      const int g = 2 * ks + kg;
      short8 af[2], bf[2];
#pragma unroll
      for (int mt = 0; mt < 2; ++mt) {
        int tokb = mt * 32 + lo;
        af[mt] = *(const short8*)(ldsA + (g * 64 + (tokb ^ (g & 31))) * 16);
      }
#pragma unroll
      for (int nt = 0; nt < 2; ++nt) bf[nt] = WfV[g * 256 + w * 64 + nt * 32 + lo];
#pragma unroll
      for (int mt = 0; mt < 2; ++mt)
#pragma unroll
        for (int nt = 0; nt < 2; ++nt)
          acc[mt][nt] = __builtin_amdgcn_mfma_f32_32x32x16_bf16(af[mt], bf[nt],
                                                                acc[mt][nt], 0, 0, 0);
    }
    // V epilogue: mask, pack to regs; after sync write vF into ldsA
    ushort4 vpk[2][2][4];
#pragma unroll
    for (int mt = 0; mt < 2; ++mt)
#pragma unroll
      for (int nt = 0; nt < 2; ++nt) {
        const float bias = nt ? bv1 : bv0;
#pragma unroll
        for (int q = 0; q < 4; ++q) {
          float vv[4];
#pragma unroll
          for (int j2 = 0; j2 < 4; ++j2) {
            int r = 4 * q + j2;
            int tok = 8 * q + 4 * kg + 32 * mt + j2;
            vv[j2] = (acc[mt][nt][r] + bias) * ldsM[tok];
          }
          vpk[mt][nt][q] = make_ushort4(f2bf(vv[0]), f2bf(vv[1]), f2bf(vv[2]), f2bf(vv[3]));
        }
      }
    __syncthreads();  // all waves done reading ldsA (V)
#pragma unroll
    for (int mt = 0; mt < 2; ++mt)
#pragma unroll
      for (int nt = 0; nt < 2; ++nt) {
        const int o = w * 64 + nt * 32 + lo;
#pragma unroll
        for (int q = 0; q < 4; ++q)
          *(ushort4*)(ldsA + ((q + 4 * mt) * 256 + o) * 16 + kg * 8) = vpk[mt][nt][q];
      }
    // no barrier needed: KV reads only this wave's d/m range (wave-private)

    // ---- KV += kf^T * v  per head (D[d][m]) ----
#pragma unroll
    for (int hh = 0; hh < 2; ++hh) {
      const int h = 2 * w + hh;
#pragma unroll
      for (int kv = 0; kv < 4; ++kv) {
        int tg = kv * 2 + kg;
        short8 akf = *(const short8*)(ldsB + (tg * 256 + h * 32 + lo) * 16);
        short8 bvf = *(const short8*)(ldsA + (tg * 256 + h * 32 + lo) * 16);
        kvacc[hh] = __builtin_amdgcn_mfma_f32_32x32x16_bf16(akf, bvf, kvacc[hh], 0, 0, 0);
      }
    }
  }

  // ---- flush ----
  float tot0 = ksacc0 + __shfl_xor(ksacc0, 32);
  float tot1 = ksacc1 + __shfl_xor(ksacc1, 32);
  if (use_atomic) {
    atomicAdd(&Ksum[b * 256 + w * 64 + (kg ? 32 : 0) + lo], kg ? tot1 : tot0);
#pragma unroll
    for (int hh = 0; hh < 2; ++hh) {
      int h = 2 * w + hh;
#pragma unroll
      for (int r = 0; r < 16; ++r) {
        int d = (r & 3) + 8 * (r >> 2) + 4 * kg;
        atomicAdd(&KV[(((size_t)b * H_ + h) * 32 + lo) * 32 + d], kvacc[hh][r]);
      }
    }
  } else {
    kspart[((size_t)b * 64 + blk) * 256 + w * 64 + (kg ? 32 : 0) + lo] = kg ? tot1 : tot0;
#pragma unroll
    for (int hh = 0; hh < 2; ++hh) {
      int h = 2 * w + hh;
      float* dst = kvpart + ((size_t)b * 64 + blk) * 8192 + ((h * 2 + kg) * 16) * 32 + lo;
#pragma unroll
      for (int r = 0; r < 16; ++r) dst[r * 32] = kvacc[hh][r];
    }
  }
}

// kR: reduce 64 block-partials per batch. grid 264 x 256.
__global__ void kR(const float* __restrict__ kvpart, const float* __restrict__ kspart,
                   float* __restrict__ KV, float* __restrict__ Ksum) {
  int idx = blockIdx.x * 256 + threadIdx.x;
  if (idx < 65536) {
    int b = idx >> 13, r2 = idx & 8191;
    int h = r2 >> 10, kg2 = (r2 >> 9) & 1, rr = (r2 >> 5) & 15, m = r2 & 31;
    const float* p = kvpart + (size_t)b * 64 * 8192 + r2;
    float s = 0.f;
#pragma unroll 8
    for (int j = 0; j < 64; ++j) s += p[(size_t)j * 8192];
    int d = (rr & 3) + 4 * kg2 + 8 * (rr >> 2);
    KV[(((size_t)b * H_ + h) * 32 + m) * 32 + d] = s;
  } else if (idx < 67584) {
    int t = idx - 65536;
    int b = t >> 8, o = t & 255;
    const float* p = kspart + (size_t)b * 64 * 256 + o;
    float s = 0.f;
#pragma unroll 8
    for (int j = 0; j < 64; ++j) s += p[j * 256];
    Ksum[t] = s;
  }
}

// kB: grid (64, B_), 256 threads, 2 tiles per block.
__global__ void __launch_bounds__(256, 2)
kB(const float* __restrict__ queries, const float* __restrict__ qmask,
   const float* __restrict__ bq, const float* __restrict__ bm,
   const short8* __restrict__ WfQ, const short8* __restrict__ WfM,
   const float* __restrict__ KV, const float* __restrict__ Ksum,
   float* __restrict__ out) {
  extern __shared__ char lds[];
  char* ldsA = lds + LDSA_OFF;
  char* ldsB = lds + LDSB_OFF;
  float* ldsM = (float*)(lds + LDSM_OFF);
  float* ldsBq = (float*)(lds + LDSBQ_OFF);
  const int tid = threadIdx.x;
  const int w = tid >> 6, lane = tid & 63, lo = lane & 31, kg = lane >> 5;
  const int blk = blockIdx.x, b = blockIdx.y;

  ldsBq[tid] = bq[tid];
  const float bm0 = bm[w * 64 + lo], bm1 = bm[w * 64 + 32 + lo];

  // hoist KV / Ksum fragments for this wave's two heads
  short8 kvf[2][2], ksf[2];
#pragma unroll
  for (int hh = 0; hh < 2; ++hh) {
    int h = 2 * w + hh;
#pragma unroll
    for (int ksd = 0; ksd < 2; ++ksd) {
      const float* p = KV + (((size_t)b * H_ + h) * 32 + lo) * 32 + ksd * 16 + kg * 8;
      short8 t;
#pragma unroll
      for (int j = 0; j < 8; ++j) t[j] = (short)f2bf(p[j]);
      kvf[hh][ksd] = t;
    }
    const float* ps = Ksum + b * 256 + h * 32 + (lane >> 4) * 8;
    short8 t2;
#pragma unroll
    for (int j = 0; j < 8; ++j) t2[j] = (short)f2bf(ps[j]);
    ksf[hh] = t2;
  }

  for (int it = 0; it < 2; ++it) {
    const int t0 = (blk * 2 + it) * 64;
    __syncthreads();
    stage_tile(queries + ((size_t)b * S_ + t0) * D_, ldsA, tid);
    if (tid < 64) ldsM[tid] = qmask[(size_t)b * S_ + t0 + tid];
    __syncthreads();

    // ---- Q projection FLIPPED: D[o][tok] = Wq * X^T ----
    f32x16 qa[2][2];
#pragma unroll
    for (int At = 0; At < 2; ++At)
#pragma unroll
      for (int Bt = 0; Bt < 2; ++Bt)
#pragma unroll
        for (int i = 0; i < 16; ++i) qa[At][Bt][i] = 0.f;
#pragma unroll 2
    for (int ks = 0; ks < 16; ++ks) {
      const int g = 2 * ks + kg;
      short8 aw[2], bx[2];
#pragma unroll
      for (int At = 0; At < 2; ++At) aw[At] = WfQ[g * 256 + w * 64 + At * 32 + lo];
#pragma unroll
      for (int Bt = 0; Bt < 2; ++Bt) {
        int tokb = Bt * 32 + lo;
        bx[Bt] = *(const short8*)(ldsA + (g * 64 + (tokb ^ (g & 31))) * 16);
      }
#pragma unroll
      for (int At = 0; At < 2; ++At)
#pragma unroll
        for (int Bt = 0; Bt < 2; ++Bt)
          qa[At][Bt] = __builtin_amdgcn_mfma_f32_32x32x16_bf16(aw[At], bx[Bt],
                                                               qa[At][Bt], 0, 0, 0);
    }
    __syncthreads();  // all waves done with ldsA (Q) -> voF may overwrite later

    // epilogue: bias + elu+1 + qmask -> qfF (ldsB, wave-private gd range)
#pragma unroll
    for (int At = 0; At < 2; ++At)
#pragma unroll
      for (int Bt = 0; Bt < 2; ++Bt) {
        int tok = Bt * 32 + lo;
        float qm = ldsM[tok];
#pragma unroll
        for (int q = 0; q < 4; ++q) {
          float vv[4];
#pragma unroll
          for (int j2 = 0; j2 < 4; ++j2) {
            int r = 4 * q + j2;
            int o = 8 * q + 4 * kg + 32 * At + 64 * w + j2;
            float f = qa[At][Bt][r] + ldsBq[o];
            f = f > 0.f ? f + 1.f : __expf(f);
            vv[j2] = f * qm;
          }
          *(ushort4*)(ldsB + ((q + 4 * At + 8 * w) * 64 + tok) * 16 + kg * 8) =
              make_ushort4(f2bf(vv[0]), f2bf(vv[1]), f2bf(vv[2]), f2bf(vv[3]));
        }
      }
    // no barrier: qfF chunks read below are wave-private

    // ---- num (flipped, D[m][tok]) and z (16x16x32) ----
    f32x16 pn[2][2];
    f32x4 pz[2][4];
#pragma unroll
    for (int hh = 0; hh < 2; ++hh) {
#pragma unroll
      for (int nt2 = 0; nt2 < 2; ++nt2)
#pragma unroll
        for (int i = 0; i < 16; ++i) pn[hh][nt2][i] = 0.f;
#pragma unroll
      for (int zt = 0; zt < 4; ++zt)
#pragma unroll
        for (int i = 0; i < 4; ++i) pz[hh][zt][i] = 0.f;
    }
#pragma unroll
    for (int hh = 0; hh < 2; ++hh) {
      int h = 2 * w + hh;
#pragma unroll
      for (int nt2 = 0; nt2 < 2; ++nt2)
#pragma unroll
        for (int ksd = 0; ksd < 2; ++ksd) {
          short8 bq8 = *(const short8*)(ldsB +
                        ((h * 4 + ksd * 2 + kg) * 64 + nt2 * 32 + lo) * 16);
          pn[hh][nt2] = __builtin_amdgcn_mfma_f32_32x32x16_bf16(kvf[hh][ksd], bq8,
                                                                pn[hh][nt2], 0, 0, 0);
        }
#pragma unroll
      for (int zt = 0; zt < 4; ++zt) {
        short8 bz = *(const short8*)(ldsB +
                      ((h * 4 + (lane >> 4)) * 64 + zt * 16 + (lane & 15)) * 16);
        pz[hh][zt] = __builtin_amdgcn_mfma_f32_16x16x32_bf16(ksf[hh], bz,
                                                             pz[hh][zt], 0, 0, 0);
      }
    }

    // ---- divide, pack vo -> voF (ldsA) ----
#pragma unroll
    for (int hh = 0; hh < 2; ++hh) {
      int h = 2 * w + hh;
#pragma unroll
      for (int nt2 = 0; nt2 < 2; ++nt2) {
        int tok = nt2 * 32 + lo;
        float z = (lane & 16) ? pz[hh][nt2 * 2 + 1][0] : pz[hh][nt2 * 2][0];
        float inv = 1.0f / (z + EPS_);
#pragma unroll
        for (int q = 0; q < 4; ++q) {
          float vv[4];
#pragma unroll
          for (int j2 = 0; j2 < 4; ++j2) vv[j2] = pn[hh][nt2][4 * q + j2] * inv;
          *(ushort4*)(ldsA + ((h * 4 + q) * 64 + tok) * 16 + kg * 8) =
              make_ushort4(f2bf(vv[0]), f2bf(vv[1]), f2bf(vv[2]), f2bf(vv[3]));
        }
      }
    }
    __syncthreads();  // voF complete (read cross-wave below)

    // ---- out GEMM (standard): D[tok][o] = vo * Wm^T ----
    f32x16 oa[2][2];
#pragma unroll
    for (int mt = 0; mt < 2; ++mt)
#pragma unroll
      for (int nt2 = 0; nt2 < 2; ++nt2)
#pragma unroll
        for (int i = 0; i < 16; ++i) oa[mt][nt2][i] = 0.f;
#pragma unroll 2
    for (int ks = 0; ks < 16; ++ks) {
      const int g = 2 * ks + kg;
      short8 av[2], bw[2];
#pragma unroll
      for (int mt = 0; mt < 2; ++mt)
        av[mt] = *(const short8*)(ldsA + (g * 64 + mt * 32 + lo) * 16);
#pragma unroll
      for (int nt2 = 0; nt2 < 2; ++nt2) bw[nt2] = WfM[g * 256 + w * 64 + nt2 * 32 + lo];
#pragma unroll
      for (int mt = 0; mt < 2; ++mt)
#pragma unroll
        for (int nt2 = 0; nt2 < 2; ++nt2)
          oa[mt][nt2] = __builtin_amdgcn_mfma_f32_32x32x16_bf16(av[mt], bw[nt2],
                                                                oa[mt][nt2], 0, 0, 0);
    }
    // epilogue: + bm, coalesced f32 stores
#pragma unroll
    for (int mt = 0; mt < 2; ++mt)
#pragma unroll
      for (int nt2 = 0; nt2 < 2; ++nt2) {
        const float bias = nt2 ? bm1 : bm0;
        const int o = w * 64 + nt2 * 32 + lo;
        float* dst = out + ((size_t)b * S_ + t0 + 32 * mt) * D_ + o;
#pragma unroll
        for (int r = 0; r < 16; ++r) {
          int tok = (r & 3) + 8 * (r >> 2) + 4 * kg;
          dst[(size_t)tok * D_] = oa[mt][nt2][r] + bias;
        }
      }
  }
}

extern "C" void kernel_launch(void* const* d_in, const int* in_sizes, int n_in,
                              void* d_out, int out_size, void* d_ws, size_t ws_size,
                              hipStream_t stream) {
  const float* queries = (const float*)d_in[0];
  const float* keys    = (const float*)d_in[1];
  const float* values  = (const float*)d_in[2];
  const float* qmask   = (const float*)d_in[3];
  const float* kmask   = (const float*)d_in[4];
  const float* Wq = (const float*)d_in[5];
  const float* bq = (const float*)d_in[6];
  const float* Wk = (const float*)d_in[7];
  const float* bk = (const float*)d_in[8];
  const float* Wv = (const float*)d_in[9];
  const float* bv = (const float*)d_in[10];
  const float* Wm = (const float*)d_in[11];
  const float* bm = (const float*)d_in[12];
  float* out = (float*)d_out;

  char* ws = (char*)d_ws;
  unsigned short* Wf = (unsigned short*)ws;          // 512KB: 4 x [32][256][8] bf16
  float* KV   = (float*)(ws + 524288);               // 256KB: [8][8][32][32]
  float* Ksum = (float*)(ws + 786432);               // 8KB:  [8][256]
  float* kvpart = (float*)(ws + 1048576);            // 16MB: [8][64][8192]
  float* kspart = (float*)(ws + 1048576 + 16777216); // 512KB: [8][64][256]
  const size_t need = 1048576 + 16777216 + 524288;
  const int use_atomic = (ws_size < need) ? 1 : 0;

  hipFuncSetAttribute(reinterpret_cast<const void*>(kA),
                      hipFuncAttributeMaxDynamicSharedMemorySize, LDS_KA);
  hipFuncSetAttribute(reinterpret_cast<const void*>(kB),
                      hipFuncAttributeMaxDynamicSharedMemorySize, LDS_KB);

  kPrep<<<128, 256, 0, stream>>>(Wq, Wk, Wv, Wm, Wf);
  if (use_atomic) hipMemsetAsync(ws + 524288, 0, 262144 + 8192, stream);

  const short8* Wf8 = (const short8*)Wf;
  kA<<<dim3(64, B_), 256, LDS_KA, stream>>>(keys, values, kmask, bk, bv,
      Wf8 + (size_t)1 * 8192, Wf8 + (size_t)2 * 8192, kvpart, kspart, KV, Ksum, use_atomic);
  if (!use_atomic) kR<<<264, 256, 0, stream>>>(kvpart, kspart, KV, Ksum);
  kB<<<dim3(64, B_), 256, LDS_KB, stream>>>(queries, qmask, bq, bm,
      Wf8, Wf8 + (size_t)3 * 8192, KV, Ksum, out);
}